// Round 5
// baseline (294.280 us; speedup 1.0000x reference)
//
#include <hip/hip_runtime.h>
#include <hip/hip_bf16.h>

typedef unsigned short u16;
typedef unsigned int   u32;
typedef __attribute__((ext_vector_type(8))) short bf16x8;
typedef __attribute__((ext_vector_type(4))) float f32x4;

static constexpr int kS = 128, kD = 1024, kC = 65536, kN = 512, kNNZ = 262144;

__device__ __forceinline__ u16 f2bf(float x) {
  u32 u = __float_as_uint(x);
  u32 r = (u + 0x7fffu + ((u >> 16) & 1u)) >> 16;   // RTNE
  return (u16)r;
}
__device__ __forceinline__ u32 pack2(float a, float b) {
  return (u32)f2bf(a) | ((u32)f2bf(b) << 16);
}
__device__ __forceinline__ float bf_lo(u32 v) { return __uint_as_float(v << 16); }
__device__ __forceinline__ float bf_hi(u32 v) { return __uint_as_float(v & 0xffff0000u); }

// ---------------- BN stats: two-stage partial sums ----------------
__global__ void k_bn_part(const float* __restrict__ enc, const int* __restrict__ bidx,
                          const int* __restrict__ tgt, float* __restrict__ part) {
  __shared__ int offs[64];
  int n0 = blockIdx.y * 64;
  if (threadIdx.x < 64) offs[threadIdx.x] = bidx[n0 + threadIdx.x] * kS + tgt[n0 + threadIdx.x];
  __syncthreads();
  int d = blockIdx.x * 256 + threadIdx.x;
  float s = 0.f, ss = 0.f;
  for (int i = 0; i < 64; ++i) {
    float v = enc[(size_t)offs[i] * kD + d];
    s += v; ss += v * v;
  }
  part[(blockIdx.y * 2 + 0) * kD + d] = s;
  part[(blockIdx.y * 2 + 1) * kD + d] = ss;
}

__global__ void k_bn_fin(const float* __restrict__ part, float* __restrict__ mean,
                         float* __restrict__ rstd) {
  int d = blockIdx.x * 256 + threadIdx.x;
  float s = 0.f, ss = 0.f;
#pragma unroll
  for (int b = 0; b < 8; ++b) {
    s  += part[(b * 2 + 0) * kD + d];
    ss += part[(b * 2 + 1) * kD + d];
  }
  float m = s * (1.f / kN);
  float var = ss * (1.f / kN) - m * m;
  mean[d] = m;
  rstd[d] = 1.f / sqrtf(var + 1e-5f);
}

// ---------------- h0 = (g - mean) * rstd  -> bf16 ----------------
__global__ void k_bn_apply(const float* __restrict__ enc, const int* __restrict__ bidx,
                           const int* __restrict__ tgt, const float* __restrict__ mean,
                           const float* __restrict__ rstd, u16* __restrict__ h0) {
  int i = blockIdx.x * blockDim.x + threadIdx.x;
  int n = i >> 8;
  int d = (i & 255) << 2;
  size_t src = (size_t)(bidx[n] * kS + tgt[n]) * kD + d;
  float4 v  = *(const float4*)(enc + src);
  float4 mn = *(const float4*)(mean + d);
  float4 rs = *(const float4*)(rstd + d);
  u32 q0 = pack2((v.x - mn.x) * rs.x, (v.y - mn.y) * rs.y);
  u32 q1 = pack2((v.z - mn.z) * rs.z, (v.w - mn.w) * rs.w);
  *(uint2*)(h0 + (size_t)n * kD + d) = make_uint2(q0, q1);
}

// ---------------- sort: histogram / scan / scatter ----------------
__global__ void k_hist(const int* __restrict__ rows, int* __restrict__ hist) {
  int e = blockIdx.x * blockDim.x + threadIdx.x;
  if (e < kNNZ) atomicAdd(&hist[rows[e]], 1);
}

__global__ __launch_bounds__(1024) void k_scan(int* __restrict__ hist, int* __restrict__ cursor) {
  __shared__ int sm[1024];
  int t = threadIdx.x;
  int base = t * 64;
  int sum = 0;
  for (int i = 0; i < 64; ++i) sum += hist[base + i];
  sm[t] = sum;
  __syncthreads();
  for (int off = 1; off < 1024; off <<= 1) {
    int v = (t >= off) ? sm[t - off] : 0;
    __syncthreads();
    sm[t] += v;
    __syncthreads();
  }
  int run = sm[t] - sum;
  for (int i = 0; i < 64; ++i) {
    int v = hist[base + i];
    hist[base + i] = run;
    cursor[base + i] = run;
    run += v;
  }
  if (t == 1023) hist[kC] = run;
}

__global__ void k_scatter(const int* __restrict__ rows, const int* __restrict__ cols,
                          const float* __restrict__ vals, int* __restrict__ cursor,
                          int* __restrict__ scol, float* __restrict__ sval) {
  int e = blockIdx.x * blockDim.x + threadIdx.x;
  if (e < kNNZ) {
    int r = rows[e];
    int p = atomicAdd(&cursor[r], 1);
    scol[p] = cols[e];
    sval[p] = vals[e];
  }
}

// ---------------- fused GEMM: W f32 read once, convert in-reg, BM=128 x BN=512 ----------------
// 512 thr (8 waves, 2M x 4N), BK=32, single-buffer LDS 50 KB, stride 80 B (pad).
// Pipeline: [cvt+ds_write t] [issue glb loads t+1] lgkm(0) barrier [MFMA t] lgkm(0) barrier.
__global__ __launch_bounds__(512)
void k_gemm_f(const float* __restrict__ W, const u16* __restrict__ h0,
              const float* __restrict__ bias, u16* __restrict__ h1t) {
  __shared__ __align__(16) u16 Ab[128 * 40];   // [128 rows][32 k] bf16, stride 40 u16 = 80 B
  __shared__ __align__(16) u16 Bb[512 * 40];   // [512 rows][32 k]
  const int t = threadIdx.x;
  const int l = t & 63, w = t >> 6;
  const int wm = (w >> 2) * 64, wn = (w & 3) * 128;
  const int cb = blockIdx.x * 128;

  // A staging map: slots g = t, t+512; row = g>>3 (0..127), q = g&7 (float4 within 32 f32)
  const int ar = t >> 3, aq = t & 7;
  // B staging map: slots s = t + 512*i (i=0..3); row = s>>2 (0..511), q = s&3 (16B within 64 B)
  const int br = t >> 2, bq = t & 3;

  const float* gA0 = W + (size_t)(cb + ar) * kD + aq * 4;
  const float* gA1 = W + (size_t)(cb + ar + 64) * kD + aq * 4;
  const u16*   gB  = h0 + (size_t)br * kD + bq * 8;

  char* Abc = (char*)Ab;
  char* Bbc = (char*)Bb;
  u32 aw0 = ar * 80 + aq * 8, aw1 = (ar + 64) * 80 + aq * 8;
  u32 bw = br * 80 + bq * 16;

  f32x4 acc[4][8];
#pragma unroll
  for (int a = 0; a < 4; ++a)
#pragma unroll
    for (int b = 0; b < 8; ++b) acc[a][b] = (f32x4){0.f, 0.f, 0.f, 0.f};

  // prologue: prefetch kt=0 into registers
  float4 nA0 = *(const float4*)gA0;
  float4 nA1 = *(const float4*)gA1;
  uint4 nB0 = *(const uint4*)(gB);
  uint4 nB1 = *(const uint4*)(gB + 128 * kD);
  uint4 nB2 = *(const uint4*)(gB + 256 * kD);
  uint4 nB3 = *(const uint4*)(gB + 384 * kD);

#pragma unroll 1
  for (int it = 0; it < 32; ++it) {
    // ---- write phase: LDS tile for iter `it` (prev barrier guarantees LDS free) ----
    *(uint2*)(Abc + aw0) = make_uint2(pack2(nA0.x, nA0.y), pack2(nA0.z, nA0.w));
    *(uint2*)(Abc + aw1) = make_uint2(pack2(nA1.x, nA1.y), pack2(nA1.z, nA1.w));
    *(uint4*)(Bbc + bw)  = nB0;
    *(uint4*)(Bbc + bw + 128 * 80) = nB1;
    *(uint4*)(Bbc + bw + 256 * 80) = nB2;
    *(uint4*)(Bbc + bw + 384 * 80) = nB3;
    // ---- issue next-tile global loads (in flight across MFMA phase) ----
    int ktn = (it < 31) ? (it + 1) * 32 : 0;
    nA0 = *(const float4*)(gA0 + ktn);
    nA1 = *(const float4*)(gA1 + ktn);
    nB0 = *(const uint4*)(gB + ktn);
    nB1 = *(const uint4*)(gB + 128 * kD + ktn);
    nB2 = *(const uint4*)(gB + 256 * kD + ktn);
    nB3 = *(const uint4*)(gB + 384 * kD + ktn);
    // ---- writes visible to all waves ----
    asm volatile("s_waitcnt lgkmcnt(0)" ::: "memory");
    __builtin_amdgcn_s_barrier();
    __builtin_amdgcn_sched_barrier(0);
    // ---- MFMA phase ----
    bf16x8 af[4], bv[8];
#pragma unroll
    for (int mb = 0; mb < 4; ++mb)
      af[mb] = *(const bf16x8*)(Abc + (wm + mb * 16 + (l & 15)) * 80 + (l >> 4) * 16);
#pragma unroll
    for (int nb = 0; nb < 8; ++nb)
      bv[nb] = *(const bf16x8*)(Bbc + (wn + nb * 16 + (l & 15)) * 80 + (l >> 4) * 16);
#pragma unroll
    for (int mb = 0; mb < 4; ++mb)
#pragma unroll
      for (int nb = 0; nb < 8; ++nb)
        acc[mb][nb] = __builtin_amdgcn_mfma_f32_16x16x32_bf16(af[mb], bv[nb], acc[mb][nb], 0, 0, 0);
    // ---- all reads retired before next overwrite ----
    asm volatile("s_waitcnt lgkmcnt(0)" ::: "memory");
    __builtin_amdgcn_s_barrier();
    __builtin_amdgcn_sched_barrier(0);
  }

  // epilogue: + bias, swish, bf16 store (C/D map: col=lane&15, row=(lane>>4)*4+i)
#pragma unroll
  for (int mb = 0; mb < 4; ++mb) {
    int rb = wm + mb * 16 + (l >> 4) * 4;
#pragma unroll
    for (int i = 0; i < 4; ++i) {
      int c = cb + rb + i;
      float bvs = bias[c];
#pragma unroll
      for (int nb = 0; nb < 8; ++nb) {
        float x = acc[mb][nb][i] + bvs;
        float sw = x / (1.f + __expf(-x));
        h1t[(size_t)c * kN + (wn + nb * 16 + (l & 15))] = f2bf(sw);
      }
    }
  }
}

// ---------------- spmm: 32 rows/block, full N per edge, dwordx4 gathers ----------------
__global__ __launch_bounds__(512)
void k_spmm(const u16* __restrict__ h1t, const int* __restrict__ rowptr,
            const int* __restrict__ scol, const float* __restrict__ sval,
            float* __restrict__ out) {
  __shared__ float tile[32 * 512];   // XOR-swizzled, 64 KB
  int r0 = blockIdx.x * 32;
  int t = threadIdx.x, w = t >> 6, l = t & 63;
#pragma unroll
  for (int j = 0; j < 4; ++j) {
    int rl = w * 4 + j;
    int r = r0 + rl;
    uint4 hv = ((const uint4*)(h1t + (size_t)r * kN))[l];
    float a0 = bf_lo(hv.x), a1 = bf_hi(hv.x), a2 = bf_lo(hv.y), a3 = bf_hi(hv.y);
    float a4 = bf_lo(hv.z), a5 = bf_hi(hv.z), a6 = bf_lo(hv.w), a7 = bf_hi(hv.w);
    int e0 = rowptr[r], e1 = rowptr[r + 1];
    int c = 0; float v = 0.f;
    if (e0 < e1) { c = scol[e0]; v = sval[e0]; }
    for (int e = e0; e < e1; ++e) {
      uint4 cv = ((const uint4*)(h1t + (size_t)c * kN))[l];
      int cn = 0; float vn = 0.f;
      if (e + 1 < e1) { cn = scol[e + 1]; vn = sval[e + 1]; }   // prefetch
      a0 = fmaf(v, bf_lo(cv.x), a0); a1 = fmaf(v, bf_hi(cv.x), a1);
      a2 = fmaf(v, bf_lo(cv.y), a2); a3 = fmaf(v, bf_hi(cv.y), a3);
      a4 = fmaf(v, bf_lo(cv.z), a4); a5 = fmaf(v, bf_hi(cv.z), a5);
      a6 = fmaf(v, bf_lo(cv.w), a6); a7 = fmaf(v, bf_hi(cv.w), a7);
      c = cn; v = vn;
    }
    int sw = (rl & 7) << 2;          // XOR bits 2..4 keep float4 groups intact
    *(float4*)&tile[rl * 512 + ((8 * l) ^ sw)]     = make_float4(a0, a1, a2, a3);
    *(float4*)&tile[rl * 512 + ((8 * l + 4) ^ sw)] = make_float4(a4, a5, a6, a7);
  }
  __syncthreads();
  int r = l & 31;
  int swr = (r & 7) << 2;
#pragma unroll
  for (int it = 0; it < 32; ++it) {
    int n = it * 16 + w * 2 + (l >> 5);
    out[(size_t)n * kC + r0 + r] = tile[r * 512 + (n ^ swr)];
  }
}

extern "C" void kernel_launch(void* const* d_in, const int* in_sizes, int n_in,
                              void* d_out, int out_size, void* d_ws, size_t ws_size,
                              hipStream_t stream) {
  (void)in_sizes; (void)n_in; (void)out_size; (void)ws_size;
  const float* enc   = (const float*)d_in[0];
  const float* W     = (const float*)d_in[1];
  const float* bias  = (const float*)d_in[2];
  const float* Avals = (const float*)d_in[3];
  const int*   bidx  = (const int*)d_in[4];
  const int*   tgt   = (const int*)d_in[5];
  const int*   Arow  = (const int*)d_in[6];
  const int*   Acol  = Arow + kNNZ;
  float* out = (float*)d_out;

  char* ws = (char*)d_ws;
  float* mean   = (float*)(ws);                       //   4 KB
  float* rstd   = (float*)(ws + 4096);                //   4 KB
  u16*   h0     = (u16*)  (ws + 8192);                //   1 MB
  int*   rowptr = (int*)  (ws + 1056768);             // 256 KB (+1)
  int*   cursor = (int*)  (ws + 1319168);             // 256 KB
  int*   scol   = (int*)  (ws + 1581312);             //   1 MB
  float* sval   = (float*)(ws + 2629888);             //   1 MB
  float* part   = (float*)(ws + 3678464);             //  64 KB
  u16*   h1t    = (u16*)  (ws + 4194304);             //  64 MB

  hipMemsetAsync(rowptr, 0, (kC + 1) * sizeof(int), stream);
  k_bn_part<<<dim3(4, 8), 256, 0, stream>>>(enc, bidx, tgt, part);
  k_bn_fin<<<4, 256, 0, stream>>>(part, mean, rstd);
  k_bn_apply<<<512, 256, 0, stream>>>(enc, bidx, tgt, mean, rstd, h0);
  k_hist<<<kNNZ / 256, 256, 0, stream>>>(Arow, rowptr);
  k_scan<<<1, 1024, 0, stream>>>(rowptr, cursor);
  k_scatter<<<kNNZ / 256, 256, 0, stream>>>(Arow, Acol, Avals, cursor, scol, sval);
  k_gemm_f<<<kC / 128, 512, 0, stream>>>(W, h0, bias, h1t);
  k_spmm<<<kC / 32, 512, 0, stream>>>(h1t, rowptr, scol, sval, out);
}

// Round 6
// 293.429 us; speedup vs baseline: 1.0029x; 1.0029x over previous
//
#include <hip/hip_runtime.h>
#include <hip/hip_bf16.h>

typedef unsigned short u16;
typedef unsigned int   u32;
typedef __attribute__((ext_vector_type(8))) short bf16x8;
typedef __attribute__((ext_vector_type(4))) float f32x4;

static constexpr int kS = 128, kD = 1024, kC = 65536, kN = 512, kNNZ = 262144;

__device__ __forceinline__ u16 f2bf(float x) {
  u32 u = __float_as_uint(x);
  u32 r = (u + 0x7fffu + ((u >> 16) & 1u)) >> 16;   // RTNE
  return (u16)r;
}
__device__ __forceinline__ u32 pack2(float a, float b) {
  return (u32)f2bf(a) | ((u32)f2bf(b) << 16);
}
__device__ __forceinline__ float bf_lo(u32 v) { return __uint_as_float(v << 16); }
__device__ __forceinline__ float bf_hi(u32 v) { return __uint_as_float(v & 0xffff0000u); }

// ---------------- BN stats: two-stage partial sums ----------------
__global__ void k_bn_part(const float* __restrict__ enc, const int* __restrict__ bidx,
                          const int* __restrict__ tgt, float* __restrict__ part) {
  __shared__ int offs[64];
  int n0 = blockIdx.y * 64;
  if (threadIdx.x < 64) offs[threadIdx.x] = bidx[n0 + threadIdx.x] * kS + tgt[n0 + threadIdx.x];
  __syncthreads();
  int d = blockIdx.x * 256 + threadIdx.x;
  float s = 0.f, ss = 0.f;
  for (int i = 0; i < 64; ++i) {
    float v = enc[(size_t)offs[i] * kD + d];
    s += v; ss += v * v;
  }
  part[(blockIdx.y * 2 + 0) * kD + d] = s;
  part[(blockIdx.y * 2 + 1) * kD + d] = ss;
}

__global__ void k_bn_fin(const float* __restrict__ part, float* __restrict__ mean,
                         float* __restrict__ rstd) {
  int d = blockIdx.x * 256 + threadIdx.x;
  float s = 0.f, ss = 0.f;
#pragma unroll
  for (int b = 0; b < 8; ++b) {
    s  += part[(b * 2 + 0) * kD + d];
    ss += part[(b * 2 + 1) * kD + d];
  }
  float m = s * (1.f / kN);
  float var = ss * (1.f / kN) - m * m;
  mean[d] = m;
  rstd[d] = 1.f / sqrtf(var + 1e-5f);
}

// ---------------- h0 = (g - mean) * rstd  -> bf16 ----------------
__global__ void k_bn_apply(const float* __restrict__ enc, const int* __restrict__ bidx,
                           const int* __restrict__ tgt, const float* __restrict__ mean,
                           const float* __restrict__ rstd, u16* __restrict__ h0) {
  int i = blockIdx.x * blockDim.x + threadIdx.x;
  int n = i >> 8;
  int d = (i & 255) << 2;
  size_t src = (size_t)(bidx[n] * kS + tgt[n]) * kD + d;
  float4 v  = *(const float4*)(enc + src);
  float4 mn = *(const float4*)(mean + d);
  float4 rs = *(const float4*)(rstd + d);
  u32 q0 = pack2((v.x - mn.x) * rs.x, (v.y - mn.y) * rs.y);
  u32 q1 = pack2((v.z - mn.z) * rs.z, (v.w - mn.w) * rs.w);
  *(uint2*)(h0 + (size_t)n * kD + d) = make_uint2(q0, q1);
}

// ---------------- sort: histogram / scan / scatter ----------------
__global__ void k_hist(const int* __restrict__ rows, int* __restrict__ hist) {
  int e = blockIdx.x * blockDim.x + threadIdx.x;
  if (e < kNNZ) atomicAdd(&hist[rows[e]], 1);
}

__global__ __launch_bounds__(1024) void k_scan(int* __restrict__ hist, int* __restrict__ cursor) {
  __shared__ int sm[1024];
  int t = threadIdx.x;
  int base = t * 64;
  int sum = 0;
  for (int i = 0; i < 64; ++i) sum += hist[base + i];
  sm[t] = sum;
  __syncthreads();
  for (int off = 1; off < 1024; off <<= 1) {
    int v = (t >= off) ? sm[t - off] : 0;
    __syncthreads();
    sm[t] += v;
    __syncthreads();
  }
  int run = sm[t] - sum;
  for (int i = 0; i < 64; ++i) {
    int v = hist[base + i];
    hist[base + i] = run;
    cursor[base + i] = run;
    run += v;
  }
  if (t == 1023) hist[kC] = run;
}

__global__ void k_scatter(const int* __restrict__ rows, const int* __restrict__ cols,
                          const float* __restrict__ vals, int* __restrict__ cursor,
                          int* __restrict__ scol, float* __restrict__ sval) {
  int e = blockIdx.x * blockDim.x + threadIdx.x;
  if (e < kNNZ) {
    int r = rows[e];
    int p = atomicAdd(&cursor[r], 1);
    scol[p] = cols[e];
    sval[p] = vals[e];
  }
}

// ---------------- fused GEMM: W f32 read once, convert in-reg, BM=128 x BN=512 ----------------
// 512 thr (8 waves, 2M x 4N), BK=32, single-buffer LDS 50 KB, stride 80 B (pad).
// Pipeline: [cvt+ds_write t] [issue glb loads t+1] lgkm(0) barrier [MFMA t] lgkm(0) barrier.
__global__ __launch_bounds__(512)
void k_gemm_f(const float* __restrict__ W, const u16* __restrict__ h0,
              const float* __restrict__ bias, u16* __restrict__ h1t) {
  __shared__ __align__(16) u16 Ab[128 * 40];   // [128 rows][32 k] bf16, stride 40 u16 = 80 B
  __shared__ __align__(16) u16 Bb[512 * 40];   // [512 rows][32 k]
  const int t = threadIdx.x;
  const int l = t & 63, w = t >> 6;
  const int wm = (w >> 2) * 64, wn = (w & 3) * 128;
  const int cb = blockIdx.x * 128;

  // A staging map: slots g = t, t+512; row = g>>3 (0..127), q = g&7 (float4 within 32 f32)
  const int ar = t >> 3, aq = t & 7;
  // B staging map: slots s = t + 512*i (i=0..3); row = s>>2 (0..511), q = s&3 (16B within 64 B)
  const int br = t >> 2, bq = t & 3;

  const float* gA0 = W + (size_t)(cb + ar) * kD + aq * 4;
  const float* gA1 = W + (size_t)(cb + ar + 64) * kD + aq * 4;
  const u16*   gB  = h0 + (size_t)br * kD + bq * 8;

  char* Abc = (char*)Ab;
  char* Bbc = (char*)Bb;
  u32 aw0 = ar * 80 + aq * 8, aw1 = (ar + 64) * 80 + aq * 8;
  u32 bw = br * 80 + bq * 16;

  f32x4 acc[4][8];
#pragma unroll
  for (int a = 0; a < 4; ++a)
#pragma unroll
    for (int b = 0; b < 8; ++b) acc[a][b] = (f32x4){0.f, 0.f, 0.f, 0.f};

  // prologue: prefetch kt=0 into registers
  float4 nA0 = *(const float4*)gA0;
  float4 nA1 = *(const float4*)gA1;
  uint4 nB0 = *(const uint4*)(gB);
  uint4 nB1 = *(const uint4*)(gB + 128 * kD);
  uint4 nB2 = *(const uint4*)(gB + 256 * kD);
  uint4 nB3 = *(const uint4*)(gB + 384 * kD);

#pragma unroll 1
  for (int it = 0; it < 32; ++it) {
    // ---- write phase: LDS tile for iter `it` (prev barrier guarantees LDS free) ----
    *(uint2*)(Abc + aw0) = make_uint2(pack2(nA0.x, nA0.y), pack2(nA0.z, nA0.w));
    *(uint2*)(Abc + aw1) = make_uint2(pack2(nA1.x, nA1.y), pack2(nA1.z, nA1.w));
    *(uint4*)(Bbc + bw)  = nB0;
    *(uint4*)(Bbc + bw + 128 * 80) = nB1;
    *(uint4*)(Bbc + bw + 256 * 80) = nB2;
    *(uint4*)(Bbc + bw + 384 * 80) = nB3;
    // ---- issue next-tile global loads (in flight across MFMA phase) ----
    int ktn = (it < 31) ? (it + 1) * 32 : 0;
    nA0 = *(const float4*)(gA0 + ktn);
    nA1 = *(const float4*)(gA1 + ktn);
    nB0 = *(const uint4*)(gB + ktn);
    nB1 = *(const uint4*)(gB + 128 * kD + ktn);
    nB2 = *(const uint4*)(gB + 256 * kD + ktn);
    nB3 = *(const uint4*)(gB + 384 * kD + ktn);
    // ---- writes visible to all waves ----
    asm volatile("s_waitcnt lgkmcnt(0)" ::: "memory");
    __builtin_amdgcn_s_barrier();
    __builtin_amdgcn_sched_barrier(0);
    // ---- MFMA phase ----
    bf16x8 af[4], bv[8];
#pragma unroll
    for (int mb = 0; mb < 4; ++mb)
      af[mb] = *(const bf16x8*)(Abc + (wm + mb * 16 + (l & 15)) * 80 + (l >> 4) * 16);
#pragma unroll
    for (int nb = 0; nb < 8; ++nb)
      bv[nb] = *(const bf16x8*)(Bbc + (wn + nb * 16 + (l & 15)) * 80 + (l >> 4) * 16);
#pragma unroll
    for (int mb = 0; mb < 4; ++mb)
#pragma unroll
      for (int nb = 0; nb < 8; ++nb)
        acc[mb][nb] = __builtin_amdgcn_mfma_f32_16x16x32_bf16(af[mb], bv[nb], acc[mb][nb], 0, 0, 0);
    // ---- all reads retired before next overwrite ----
    asm volatile("s_waitcnt lgkmcnt(0)" ::: "memory");
    __builtin_amdgcn_s_barrier();
    __builtin_amdgcn_sched_barrier(0);
  }

  // epilogue: + bias, swish, bf16 store (C/D map: col=lane&15, row=(lane>>4)*4+i)
#pragma unroll
  for (int mb = 0; mb < 4; ++mb) {
    int rb = wm + mb * 16 + (l >> 4) * 4;
#pragma unroll
    for (int i = 0; i < 4; ++i) {
      int c = cb + rb + i;
      float bvs = bias[c];
#pragma unroll
      for (int nb = 0; nb < 8; ++nb) {
        float x = acc[mb][nb][i] + bvs;
        float sw = x / (1.f + __expf(-x));
        h1t[(size_t)c * kN + (wn + nb * 16 + (l & 15))] = f2bf(sw);
      }
    }
  }
}

// ---------------- spmm: 32 rows/block, full N per edge, dwordx4 gathers ----------------
__global__ __launch_bounds__(512)
void k_spmm(const u16* __restrict__ h1t, const int* __restrict__ rowptr,
            const int* __restrict__ scol, const float* __restrict__ sval,
            float* __restrict__ out) {
  __shared__ float tile[32 * 512];   // XOR-swizzled, 64 KB
  int r0 = blockIdx.x * 32;
  int t = threadIdx.x, w = t >> 6, l = t & 63;
#pragma unroll
  for (int j = 0; j < 4; ++j) {
    int rl = w * 4 + j;
    int r = r0 + rl;
    uint4 hv = ((const uint4*)(h1t + (size_t)r * kN))[l];
    float a0 = bf_lo(hv.x), a1 = bf_hi(hv.x), a2 = bf_lo(hv.y), a3 = bf_hi(hv.y);
    float a4 = bf_lo(hv.z), a5 = bf_hi(hv.z), a6 = bf_lo(hv.w), a7 = bf_hi(hv.w);
    int e0 = rowptr[r], e1 = rowptr[r + 1];
    int c = 0; float v = 0.f;
    if (e0 < e1) { c = scol[e0]; v = sval[e0]; }
    for (int e = e0; e < e1; ++e) {
      uint4 cv = ((const uint4*)(h1t + (size_t)c * kN))[l];
      int cn = 0; float vn = 0.f;
      if (e + 1 < e1) { cn = scol[e + 1]; vn = sval[e + 1]; }   // prefetch
      a0 = fmaf(v, bf_lo(cv.x), a0); a1 = fmaf(v, bf_hi(cv.x), a1);
      a2 = fmaf(v, bf_lo(cv.y), a2); a3 = fmaf(v, bf_hi(cv.y), a3);
      a4 = fmaf(v, bf_lo(cv.z), a4); a5 = fmaf(v, bf_hi(cv.z), a5);
      a6 = fmaf(v, bf_lo(cv.w), a6); a7 = fmaf(v, bf_hi(cv.w), a7);
      c = cn; v = vn;
    }
    int sw = (rl & 7) << 2;          // XOR bits 2..4 keep float4 groups intact
    *(float4*)&tile[rl * 512 + ((8 * l) ^ sw)]     = make_float4(a0, a1, a2, a3);
    *(float4*)&tile[rl * 512 + ((8 * l + 4) ^ sw)] = make_float4(a4, a5, a6, a7);
  }
  __syncthreads();
  int r = l & 31;
  int swr = (r & 7) << 2;
#pragma unroll
  for (int it = 0; it < 32; ++it) {
    int n = it * 16 + w * 2 + (l >> 5);
    out[(size_t)n * kC + r0 + r] = tile[r * 512 + (n ^ swr)];
  }
}

extern "C" void kernel_launch(void* const* d_in, const int* in_sizes, int n_in,
                              void* d_out, int out_size, void* d_ws, size_t ws_size,
                              hipStream_t stream) {
  (void)in_sizes; (void)n_in; (void)out_size; (void)ws_size;
  const float* enc   = (const float*)d_in[0];
  const float* W     = (const float*)d_in[1];
  const float* bias  = (const float*)d_in[2];
  const float* Avals = (const float*)d_in[3];
  const int*   bidx  = (const int*)d_in[4];
  const int*   tgt   = (const int*)d_in[5];
  const int*   Arow  = (const int*)d_in[6];
  const int*   Acol  = Arow + kNNZ;
  float* out = (float*)d_out;

  char* ws = (char*)d_ws;
  float* mean   = (float*)(ws);                       //   4 KB
  float* rstd   = (float*)(ws + 4096);                //   4 KB
  u16*   h0     = (u16*)  (ws + 8192);                //   1 MB
  int*   rowptr = (int*)  (ws + 1056768);             // 256 KB (+1)
  int*   cursor = (int*)  (ws + 1319168);             // 256 KB
  int*   scol   = (int*)  (ws + 1581312);             //   1 MB
  float* sval   = (float*)(ws + 2629888);             //   1 MB
  float* part   = (float*)(ws + 3678464);             //  64 KB
  u16*   h1t    = (u16*)  (ws + 4194304);             //  64 MB

  hipMemsetAsync(rowptr, 0, (kC + 1) * sizeof(int), stream);
  k_bn_part<<<dim3(4, 8), 256, 0, stream>>>(enc, bidx, tgt, part);
  k_bn_fin<<<4, 256, 0, stream>>>(part, mean, rstd);
  k_bn_apply<<<512, 256, 0, stream>>>(enc, bidx, tgt, mean, rstd, h0);
  k_hist<<<kNNZ / 256, 256, 0, stream>>>(Arow, rowptr);
  k_scan<<<1, 1024, 0, stream>>>(rowptr, cursor);
  k_scatter<<<kNNZ / 256, 256, 0, stream>>>(Arow, Acol, Avals, cursor, scol, sval);
  k_gemm_f<<<kC / 128, 512, 0, stream>>>(W, h0, bias, h1t);
  k_spmm<<<kC / 32, 512, 0, stream>>>(h1t, rowptr, scol, sval, out);
}

// Round 7
// 285.593 us; speedup vs baseline: 1.0304x; 1.0274x over previous
//
#include <hip/hip_runtime.h>
#include <hip/hip_bf16.h>

typedef unsigned short u16;
typedef unsigned int   u32;
typedef __attribute__((ext_vector_type(8))) short bf16x8;
typedef __attribute__((ext_vector_type(4))) float f32x4;

static constexpr int kS = 128, kD = 1024, kC = 65536, kN = 512, kNNZ = 262144;

__device__ __forceinline__ u16 f2bf(float x) {
  u32 u = __float_as_uint(x);
  u32 r = (u + 0x7fffu + ((u >> 16) & 1u)) >> 16;   // RTNE
  return (u16)r;
}
__device__ __forceinline__ u32 pack2(float a, float b) {
  return (u32)f2bf(a) | ((u32)f2bf(b) << 16);
}
__device__ __forceinline__ float bf_lo(u32 v) { return __uint_as_float(v << 16); }
__device__ __forceinline__ float bf_hi(u32 v) { return __uint_as_float(v & 0xffff0000u); }

// ---------------- BN stats: two-stage partial sums ----------------
__global__ void k_bn_part(const float* __restrict__ enc, const int* __restrict__ bidx,
                          const int* __restrict__ tgt, float* __restrict__ part) {
  __shared__ int offs[64];
  int n0 = blockIdx.y * 64;
  if (threadIdx.x < 64) offs[threadIdx.x] = bidx[n0 + threadIdx.x] * kS + tgt[n0 + threadIdx.x];
  __syncthreads();
  int d = blockIdx.x * 256 + threadIdx.x;
  float s = 0.f, ss = 0.f;
  for (int i = 0; i < 64; ++i) {
    float v = enc[(size_t)offs[i] * kD + d];
    s += v; ss += v * v;
  }
  part[(blockIdx.y * 2 + 0) * kD + d] = s;
  part[(blockIdx.y * 2 + 1) * kD + d] = ss;
}

__global__ void k_bn_fin(const float* __restrict__ part, float* __restrict__ mean,
                         float* __restrict__ rstd) {
  int d = blockIdx.x * 256 + threadIdx.x;
  float s = 0.f, ss = 0.f;
#pragma unroll
  for (int b = 0; b < 8; ++b) {
    s  += part[(b * 2 + 0) * kD + d];
    ss += part[(b * 2 + 1) * kD + d];
  }
  float m = s * (1.f / kN);
  float var = ss * (1.f / kN) - m * m;
  mean[d] = m;
  rstd[d] = 1.f / sqrtf(var + 1e-5f);
}

// ---------------- BN apply + pack into fragment-major Bp ----------------
// Bp entry (kt, q, n) at flat (kt*4+q)*512+n, 8 bf16 = h0[n][kt*32+q*8 .. +8]
__global__ void k_bn_pack(const float* __restrict__ enc, const int* __restrict__ bidx,
                          const int* __restrict__ tgt, const float* __restrict__ mean,
                          const float* __restrict__ rstd, u16* __restrict__ Bp) {
  int i = blockIdx.x * 256 + threadIdx.x;     // 256 blocks x 256 = 65536 entries
  int n = i & 511;
  int g = i >> 9;                              // g = kt*4+q, k0 = g*8
  int k0 = g * 8;
  size_t src = (size_t)(bidx[n] * kS + tgt[n]) * kD + k0;
  float4 v0 = *(const float4*)(enc + src);
  float4 v1 = *(const float4*)(enc + src + 4);
  float4 m0 = *(const float4*)(mean + k0);
  float4 m1 = *(const float4*)(mean + k0 + 4);
  float4 r0 = *(const float4*)(rstd + k0);
  float4 r1 = *(const float4*)(rstd + k0 + 4);
  u32 q0 = pack2((v0.x - m0.x) * r0.x, (v0.y - m0.y) * r0.y);
  u32 q1 = pack2((v0.z - m0.z) * r0.z, (v0.w - m0.w) * r0.w);
  u32 q2 = pack2((v1.x - m1.x) * r1.x, (v1.y - m1.y) * r1.y);
  u32 q3 = pack2((v1.z - m1.z) * r1.z, (v1.w - m1.w) * r1.w);
  *(uint4*)(Bp + (size_t)i * 8) = make_uint4(q0, q1, q2, q3);
}

// ---------------- sort: histogram / scan / scatter ----------------
__global__ void k_hist(const int* __restrict__ rows, int* __restrict__ hist) {
  int e = blockIdx.x * blockDim.x + threadIdx.x;
  if (e < kNNZ) atomicAdd(&hist[rows[e]], 1);
}

__global__ __launch_bounds__(1024) void k_scan(int* __restrict__ hist, int* __restrict__ cursor) {
  __shared__ int sm[1024];
  int t = threadIdx.x;
  int base = t * 64;
  int sum = 0;
  for (int i = 0; i < 64; ++i) sum += hist[base + i];
  sm[t] = sum;
  __syncthreads();
  for (int off = 1; off < 1024; off <<= 1) {
    int v = (t >= off) ? sm[t - off] : 0;
    __syncthreads();
    sm[t] += v;
    __syncthreads();
  }
  int run = sm[t] - sum;
  for (int i = 0; i < 64; ++i) {
    int v = hist[base + i];
    hist[base + i] = run;
    cursor[base + i] = run;
    run += v;
  }
  if (t == 1023) hist[kC] = run;
}

__global__ void k_scatter(const int* __restrict__ rows, const int* __restrict__ cols,
                          const float* __restrict__ vals, int* __restrict__ cursor,
                          int* __restrict__ scol, float* __restrict__ sval) {
  int e = blockIdx.x * blockDim.x + threadIdx.x;
  if (e < kNNZ) {
    int r = rows[e];
    int p = atomicAdd(&cursor[r], 1);
    scol[p] = cols[e];
    sval[p] = vals[e];
  }
}

// ---------------- fused GEMM v2: 1024 thr, BM=128 x BN=512, B direct global->reg ----------------
// 16 waves (2M x 8N), acc[4][4]=64 f32/thr, A dbuf-LDS (2x9KB), one barrier/K-step,
// bv 2-phase-ahead prefetch by parity -> counted vmcnt, never drained.
__global__ __launch_bounds__(1024)
void k_gemm_f2(const float* __restrict__ W, const u16* __restrict__ Bp,
               const float* __restrict__ bias, u16* __restrict__ h1t) {
  __shared__ __align__(16) u16 Ab0[128 * 36];   // 32 k bf16/row, stride 36 u16 = 72 B
  __shared__ __align__(16) u16 Ab1[128 * 36];
  const int t = threadIdx.x;
  const int l = t & 63;
  const int w = t >> 6;                         // 0..15
  const int wm = (w >> 3) * 64, wn = (w & 7) * 64;
  const int cb = blockIdx.x * 128;
  const int ar = t >> 3, aq = t & 7;            // A stage: 128 rows x 8 float4 slots
  const int q = l >> 4, ln = l & 15;
  const float* gA = W + (size_t)(cb + ar) * kD + aq * 4;
  u16* awp0 = Ab0 + ar * 36 + aq * 4;
  u16* awp1 = Ab1 + ar * 36 + aq * 4;
  const u16* gB = Bp + ((size_t)q * 512 + wn + ln) * 8;   // + kt*16384 + nb*128

  f32x4 acc[4][4];
#pragma unroll
  for (int a = 0; a < 4; ++a)
#pragma unroll
    for (int b = 0; b < 4; ++b) acc[a][b] = (f32x4){0.f, 0.f, 0.f, 0.f};

  float4 fA;
  bf16x8 bvA[4], bvB[4];

  // prologue: stage kt=0 into Ab0; load bv(0) and bv(1); prefetch A(1)
  fA = *(const float4*)(gA);
#pragma unroll
  for (int nb = 0; nb < 4; ++nb) bvA[nb] = *(const bf16x8*)(gB + nb * 128);
  *(uint2*)awp0 = make_uint2(pack2(fA.x, fA.y), pack2(fA.z, fA.w));
  fA = *(const float4*)(gA + 32);
#pragma unroll
  for (int nb = 0; nb < 4; ++nb) bvB[nb] = *(const bf16x8*)(gB + 16384 + nb * 128);
  asm volatile("s_waitcnt lgkmcnt(0)" ::: "memory");
  __builtin_amdgcn_s_barrier();
  __builtin_amdgcn_sched_barrier(0);

#pragma unroll 1
  for (int tt = 0; tt < 16; ++tt) {
    // ---- even phase t=2*tt: compute from Ab0/bvA; stage t+1->Ab1; load t+2->fA,bvA ----
    {
#pragma unroll
      for (int mb = 0; mb < 4; ++mb) {
        bf16x8 af = *(const bf16x8*)(Ab0 + (wm + mb * 16 + ln) * 36 + q * 8);
#pragma unroll
        for (int nb = 0; nb < 4; ++nb)
          acc[mb][nb] = __builtin_amdgcn_mfma_f32_16x16x32_bf16(af, bvA[nb], acc[mb][nb], 0, 0, 0);
      }
      *(uint2*)awp1 = make_uint2(pack2(fA.x, fA.y), pack2(fA.z, fA.w));   // waits fA(t+1), vmcnt counted
      int ktn = (2 * tt + 2) & 31;                                        // tt=15 clamps harmlessly
      fA = *(const float4*)(gA + ktn * 32);
#pragma unroll
      for (int nb = 0; nb < 4; ++nb)
        bvA[nb] = *(const bf16x8*)(gB + (size_t)ktn * 16384 + nb * 128);
      asm volatile("s_waitcnt lgkmcnt(0)" ::: "memory");
      __builtin_amdgcn_s_barrier();
      __builtin_amdgcn_sched_barrier(0);
    }
    // ---- odd phase t=2*tt+1: compute from Ab1/bvB; stage t+2->Ab0; load t+3->fA,bvB ----
    {
#pragma unroll
      for (int mb = 0; mb < 4; ++mb) {
        bf16x8 af = *(const bf16x8*)(Ab1 + (wm + mb * 16 + ln) * 36 + q * 8);
#pragma unroll
        for (int nb = 0; nb < 4; ++nb)
          acc[mb][nb] = __builtin_amdgcn_mfma_f32_16x16x32_bf16(af, bvB[nb], acc[mb][nb], 0, 0, 0);
      }
      if (tt < 15) {
        *(uint2*)awp0 = make_uint2(pack2(fA.x, fA.y), pack2(fA.z, fA.w));
        int ktn = 2 * tt + 3;
        fA = *(const float4*)(gA + ktn * 32);
#pragma unroll
        for (int nb = 0; nb < 4; ++nb)
          bvB[nb] = *(const bf16x8*)(gB + (size_t)ktn * 16384 + nb * 128);
        asm volatile("s_waitcnt lgkmcnt(0)" ::: "memory");
        __builtin_amdgcn_s_barrier();
        __builtin_amdgcn_sched_barrier(0);
      }
    }
  }

  // epilogue: + bias, swish, bf16 store (C/D map: col=lane&15, row=(lane>>4)*4+i)
#pragma unroll
  for (int mb = 0; mb < 4; ++mb) {
    int rb = wm + mb * 16 + q * 4;
#pragma unroll
    for (int i = 0; i < 4; ++i) {
      int c = cb + rb + i;
      float bvs = bias[c];
#pragma unroll
      for (int nb = 0; nb < 4; ++nb) {
        float x = acc[mb][nb][i] + bvs;
        float sw = x / (1.f + __expf(-x));
        h1t[(size_t)c * kN + (wn + nb * 16 + ln)] = f2bf(sw);
      }
    }
  }
}

// ---------------- spmm: 32 rows/block, full N per edge, dwordx4 gathers ----------------
__global__ __launch_bounds__(512)
void k_spmm(const u16* __restrict__ h1t, const int* __restrict__ rowptr,
            const int* __restrict__ scol, const float* __restrict__ sval,
            float* __restrict__ out) {
  __shared__ float tile[32 * 512];   // XOR-swizzled, 64 KB
  int r0 = blockIdx.x * 32;
  int t = threadIdx.x, w = t >> 6, l = t & 63;
#pragma unroll
  for (int j = 0; j < 4; ++j) {
    int rl = w * 4 + j;
    int r = r0 + rl;
    uint4 hv = ((const uint4*)(h1t + (size_t)r * kN))[l];
    float a0 = bf_lo(hv.x), a1 = bf_hi(hv.x), a2 = bf_lo(hv.y), a3 = bf_hi(hv.y);
    float a4 = bf_lo(hv.z), a5 = bf_hi(hv.z), a6 = bf_lo(hv.w), a7 = bf_hi(hv.w);
    int e0 = rowptr[r], e1 = rowptr[r + 1];
    int c = 0; float v = 0.f;
    if (e0 < e1) { c = scol[e0]; v = sval[e0]; }
    for (int e = e0; e < e1; ++e) {
      uint4 cv = ((const uint4*)(h1t + (size_t)c * kN))[l];
      int cn = 0; float vn = 0.f;
      if (e + 1 < e1) { cn = scol[e + 1]; vn = sval[e + 1]; }   // prefetch
      a0 = fmaf(v, bf_lo(cv.x), a0); a1 = fmaf(v, bf_hi(cv.x), a1);
      a2 = fmaf(v, bf_lo(cv.y), a2); a3 = fmaf(v, bf_hi(cv.y), a3);
      a4 = fmaf(v, bf_lo(cv.z), a4); a5 = fmaf(v, bf_hi(cv.z), a5);
      a6 = fmaf(v, bf_lo(cv.w), a6); a7 = fmaf(v, bf_hi(cv.w), a7);
      c = cn; v = vn;
    }
    int sw = (rl & 7) << 2;          // XOR bits 2..4 keep float4 groups intact
    *(float4*)&tile[rl * 512 + ((8 * l) ^ sw)]     = make_float4(a0, a1, a2, a3);
    *(float4*)&tile[rl * 512 + ((8 * l + 4) ^ sw)] = make_float4(a4, a5, a6, a7);
  }
  __syncthreads();
  int r = l & 31;
  int swr = (r & 7) << 2;
#pragma unroll
  for (int it = 0; it < 32; ++it) {
    int n = it * 16 + w * 2 + (l >> 5);
    out[(size_t)n * kC + r0 + r] = tile[r * 512 + (n ^ swr)];
  }
}

extern "C" void kernel_launch(void* const* d_in, const int* in_sizes, int n_in,
                              void* d_out, int out_size, void* d_ws, size_t ws_size,
                              hipStream_t stream) {
  (void)in_sizes; (void)n_in; (void)out_size; (void)ws_size;
  const float* enc   = (const float*)d_in[0];
  const float* W     = (const float*)d_in[1];
  const float* bias  = (const float*)d_in[2];
  const float* Avals = (const float*)d_in[3];
  const int*   bidx  = (const int*)d_in[4];
  const int*   tgt   = (const int*)d_in[5];
  const int*   Arow  = (const int*)d_in[6];
  const int*   Acol  = Arow + kNNZ;
  float* out = (float*)d_out;

  char* ws = (char*)d_ws;
  float* mean   = (float*)(ws);                       //   4 KB
  float* rstd   = (float*)(ws + 4096);                //   4 KB
  u16*   Bp     = (u16*)  (ws + 8192);                //   1 MB fragment-major h0
  int*   rowptr = (int*)  (ws + 1056768);             // 256 KB (+1)
  int*   cursor = (int*)  (ws + 1319168);             // 256 KB
  int*   scol   = (int*)  (ws + 1581312);             //   1 MB
  float* sval   = (float*)(ws + 2629888);             //   1 MB
  float* part   = (float*)(ws + 3678464);             //  64 KB
  u16*   h1t    = (u16*)  (ws + 4194304);             //  64 MB

  hipMemsetAsync(rowptr, 0, (kC + 1) * sizeof(int), stream);
  k_bn_part<<<dim3(4, 8), 256, 0, stream>>>(enc, bidx, tgt, part);
  k_bn_fin<<<4, 256, 0, stream>>>(part, mean, rstd);
  k_bn_pack<<<256, 256, 0, stream>>>(enc, bidx, tgt, mean, rstd, Bp);
  k_hist<<<kNNZ / 256, 256, 0, stream>>>(Arow, rowptr);
  k_scan<<<1, 1024, 0, stream>>>(rowptr, cursor);
  k_scatter<<<kNNZ / 256, 256, 0, stream>>>(Arow, Acol, Avals, cursor, scol, sval);
  k_gemm_f2<<<kC / 128, 1024, 0, stream>>>(W, Bp, bias, h1t);
  k_spmm<<<kC / 32, 512, 0, stream>>>(h1t, rowptr, scol, sval, out);
}